// Round 1
// baseline (186.611 us; speedup 1.0000x reference)
//
#include <hip/hip_runtime.h>
#include <math.h>

// SSIM fused kernel for MI355X (gfx950).
// A,B: [16,3,512,512] f32. Output: scalar f32 = mean(ssim_map).
// Separable 11-tap Gaussian; zero-padded SAME conv (matches jax.lax.conv).

#define TX 64            // tile width (outputs)
#define TY 32            // tile height (outputs)
#define SR 42            // TY + 10 rows of horizontal-conv results
#define HSTRIDE 65       // padded from 64: makes LDS stores/reads 2-way (free)
#define IMG_H 512
#define IMG_W 512
#define C1F 1.0e-4f      // 0.01^2
#define C2F 9.0e-4f      // 0.03^2

__global__ void ssim_zero(double* acc) { *acc = 0.0; }

__global__ void ssim_finalize(const double* acc, float* out) {
    *out = (float)(*acc / 12582912.0);   // 16*3*512*512
}

__global__ __launch_bounds__(256, 3)
void ssim_main(const float* __restrict__ A, const float* __restrict__ B,
               double* __restrict__ acc)
{
    // 5 horizontal-conv planes: hA, hB, hAA, hBB, hAB  (54,600 B -> 3 blk/CU)
    __shared__ float h[5][SR * HSTRIDE];

    const int t  = threadIdx.x;
    const int x0 = blockIdx.x * TX;
    const int y0 = blockIdx.y * TY;
    const size_t pbase = (size_t)blockIdx.z * (size_t)(IMG_H * IMG_W);
    const float* __restrict__ pa = A + pbase;
    const float* __restrict__ pb = B + pbase;

    // Gaussian weights, same fp32 formula as reference (2*sigma^2 = 4.5 exact)
    float g[11];
    {
        float gs = 0.f;
        #pragma unroll
        for (int i = 0; i < 11; ++i) {
            const float d = (float)(i - 5);
            g[i] = expf(-d * d / 4.5f);
            gs += g[i];
        }
        #pragma unroll
        for (int i = 0; i < 11; ++i) g[i] /= gs;
    }

    // ---------------- horizontal pass ----------------
    // 168 active threads: thread t -> row r = t/4 (0..41), 16-col segment.
    // Sliding-window in registers: 26 loads -> 16 outputs x 5 signals.
    if (t < 168) {
        const int r   = t >> 2;
        const int c0  = (t & 3) << 4;
        const int gy  = y0 - 5 + r;
        const int gxb = x0 - 5 + c0;
        const bool rowok = ((unsigned)gy < (unsigned)IMG_H);
        const float* __restrict__ ra = pa + (ptrdiff_t)gy * IMG_W;
        const float* __restrict__ rb = pb + (ptrdiff_t)gy * IMG_W;

        float a[26], b[26];
        if (rowok && gxb >= 0 && gxb + 25 < IMG_W) {
            // interior fast path: unchecked loads
            #pragma unroll
            for (int j = 0; j < 26; ++j) {
                a[j] = ra[gxb + j];
                b[j] = rb[gxb + j];
            }
        } else {
            #pragma unroll
            for (int j = 0; j < 26; ++j) {
                const int gx = gxb + j;
                const bool ok = rowok && ((unsigned)gx < (unsigned)IMG_W);
                a[j] = ok ? ra[gx] : 0.f;
                b[j] = ok ? rb[gx] : 0.f;
            }
        }

        #pragma unroll
        for (int p = 0; p < 16; ++p) {
            float sa = 0.f, sb = 0.f, saa = 0.f, sbb = 0.f, sab = 0.f;
            #pragma unroll
            for (int k = 0; k < 11; ++k) {
                const float w  = g[k];
                const float av = a[p + k];
                const float bv = b[p + k];
                sa  += w * av;
                sb  += w * bv;
                saa += w * (av * av);
                sbb += w * (bv * bv);
                sab += w * (av * bv);
            }
            const int o = r * HSTRIDE + c0 + p;
            h[0][o] = sa;  h[1][o] = sb;
            h[2][o] = saa; h[3][o] = sbb; h[4][o] = sab;
        }
    }
    __syncthreads();

    // ---------------- vertical pass + SSIM ----------------
    // 256 threads: thread t -> column x = t&63, rows yb..yb+7.
    // Stream 18 h-rows; static-indexed accumulators stay in registers.
    float lsum = 0.f;
    {
        const int x  = t & 63;
        const int yb = (t >> 6) << 3;
        float m1[8], m2[8], ea[8], eb[8], ec[8];
        #pragma unroll
        for (int j = 0; j < 8; ++j) { m1[j]=0.f; m2[j]=0.f; ea[j]=0.f; eb[j]=0.f; ec[j]=0.f; }

        #pragma unroll
        for (int k = 0; k < 18; ++k) {
            const int o = (yb + k) * HSTRIDE + x;
            const float vA  = h[0][o];
            const float vB  = h[1][o];
            const float vAA = h[2][o];
            const float vBB = h[3][o];
            const float vAB = h[4][o];
            #pragma unroll
            for (int j = 0; j < 8; ++j) {
                const int kk = k - j;
                if (kk >= 0 && kk < 11) {
                    const float w = g[kk];
                    m1[j] += w * vA;  m2[j] += w * vB;
                    ea[j] += w * vAA; eb[j] += w * vBB; ec[j] += w * vAB;
                }
            }
        }

        #pragma unroll
        for (int j = 0; j < 8; ++j) {
            const float mu1 = m1[j], mu2 = m2[j];
            const float mu1s = mu1 * mu1, mu2s = mu2 * mu2, mu12 = mu1 * mu2;
            const float s1  = ea[j] - mu1s;
            const float s2  = eb[j] - mu2s;
            const float s12 = ec[j] - mu12;
            const float num = (2.f * mu12 + C1F) * (2.f * s12 + C2F);
            const float den = (mu1s + mu2s + C1F) * (s1 + s2 + C2F);
            lsum += num / den;
        }
    }

    // ---------------- reduction ----------------
    #pragma unroll
    for (int off = 32; off > 0; off >>= 1)
        lsum += __shfl_down(lsum, off, 64);

    __syncthreads();                 // all LDS reads done; reuse h[0] for partials
    if ((t & 63) == 0) h[0][t >> 6] = lsum;
    __syncthreads();
    if (t == 0) {
        const double bs = (double)h[0][0] + (double)h[0][1]
                        + (double)h[0][2] + (double)h[0][3];
        atomicAdd(acc, bs);
    }
}

extern "C" void kernel_launch(void* const* d_in, const int* in_sizes, int n_in,
                              void* d_out, int out_size, void* d_ws, size_t ws_size,
                              hipStream_t stream) {
    const float* A = (const float*)d_in[0];
    const float* B = (const float*)d_in[1];
    float* out  = (float*)d_out;
    double* acc = (double*)d_ws;

    ssim_zero<<<dim3(1), dim3(1), 0, stream>>>(acc);
    dim3 grid(IMG_W / TX, IMG_H / TY, 48);   // (8, 16, 48) = 6144 blocks
    ssim_main<<<grid, dim3(256), 0, stream>>>(A, B, acc);
    ssim_finalize<<<dim3(1), dim3(1), 0, stream>>>(acc, out);
}